// Round 1
// baseline (351.485 us; speedup 1.0000x reference)
//
#include <hip/hip_runtime.h>
#include <math.h>

#define B 128
#define S 32
#define Dm 128
#define NV (B * S)
#define MARGINF 0.3f

// ---------------------------------------------------------------------------
// K1: L2-normalize each of the 4096 vectors (dim 128); also store sq = sum(x^2)
// after normalization (matches reference, which recomputes sq on normalized x).
// One wave (64 lanes) per vector; lane l handles elements l and l+64.
// ---------------------------------------------------------------------------
__global__ __launch_bounds__(64) void norm_kernel(const float* __restrict__ X,
                                                  float* __restrict__ Xn,
                                                  float* __restrict__ sqv) {
    int v = blockIdx.x;
    int l = threadIdx.x;
    const float* xr = X + (size_t)v * Dm;
    float a = xr[l];
    float b = xr[l + 64];
    float ss = a * a + b * b;
    for (int off = 32; off >= 1; off >>= 1) ss += __shfl_down(ss, off);
    ss = __shfl(ss, 0);
    float nrm = sqrtf(ss);
    float inv = 1.0f / fmaxf(nrm, 1e-12f);
    Xn[(size_t)v * Dm + l] = a * inv;
    Xn[(size_t)v * Dm + l + 64] = b * inv;
    if (l == 0) sqv[v] = ss * inv * inv;
}

// ---------------------------------------------------------------------------
// K2: for each unordered block pair (i <= j), compute the 32x32 matrix
//   E[p][q] = exp(sqrt(clip(sq_i[p] + sq_j[q] - 2 * <x_i_p, x_j_q>, 1e-12)))
// then write
//   rowsum[i][j][p] = sum_q E[p][q],  rowmin[i][j][p] = min_q E[p][q]
//   rowsum[j][i][q] = sum_p E[p][q],  rowmin[j][i][q] = min_p E[p][q]  (i != j)
// (block (j,i) stats are the transpose stats of block (i,j)).
// 256 threads; each thread computes a 2x2 tile of the 32x32 gram.
// ---------------------------------------------------------------------------
__global__ __launch_bounds__(256) void pair_block_kernel(const float* __restrict__ Xn,
                                                         const float* __restrict__ sqv,
                                                         float* __restrict__ rowsum,
                                                         float* __restrict__ rowmin) {
    int j = blockIdx.x;
    int i = blockIdx.y;
    if (i > j) return;

    __shared__ float Xi[S * Dm];
    __shared__ float Xj[S * Dm];
    __shared__ float Et[S][S + 1];

    int t = threadIdx.x;

    // Stage the two 32x128 operand panels (each contiguous 16 KB in Xn).
    {
        const float4* si = (const float4*)(Xn + (size_t)i * S * Dm);
        const float4* sj = (const float4*)(Xn + (size_t)j * S * Dm);
        float4* di = (float4*)Xi;
        float4* dj = (float4*)Xj;
        for (int k = t; k < S * Dm / 4; k += 256) {
            di[k] = si[k];
            dj[k] = sj[k];
        }
    }
    __syncthreads();

    int p0 = (t >> 4) * 2;
    int q0 = (t & 15) * 2;

    float acc00 = 0.f, acc01 = 0.f, acc10 = 0.f, acc11 = 0.f;
    const float4* ri0 = (const float4*)(Xi + p0 * Dm);
    const float4* ri1 = (const float4*)(Xi + (p0 + 1) * Dm);
    const float4* rj0 = (const float4*)(Xj + q0 * Dm);
    const float4* rj1 = (const float4*)(Xj + (q0 + 1) * Dm);
#pragma unroll 8
    for (int k = 0; k < Dm / 4; ++k) {
        float4 a0 = ri0[k], a1 = ri1[k], b0 = rj0[k], b1 = rj1[k];
        acc00 += a0.x * b0.x + a0.y * b0.y + a0.z * b0.z + a0.w * b0.w;
        acc01 += a0.x * b1.x + a0.y * b1.y + a0.z * b1.z + a0.w * b1.w;
        acc10 += a1.x * b0.x + a1.y * b0.y + a1.z * b0.z + a1.w * b0.w;
        acc11 += a1.x * b1.x + a1.y * b1.y + a1.z * b1.z + a1.w * b1.w;
    }

    float si0 = sqv[i * S + p0], si1 = sqv[i * S + p0 + 1];
    float sj0 = sqv[j * S + q0], sj1 = sqv[j * S + q0 + 1];

    Et[p0][q0]         = expf(sqrtf(fmaxf(si0 + sj0 - 2.f * acc00, 1e-12f)));
    Et[p0][q0 + 1]     = expf(sqrtf(fmaxf(si0 + sj1 - 2.f * acc01, 1e-12f)));
    Et[p0 + 1][q0]     = expf(sqrtf(fmaxf(si1 + sj0 - 2.f * acc10, 1e-12f)));
    Et[p0 + 1][q0 + 1] = expf(sqrtf(fmaxf(si1 + sj1 - 2.f * acc11, 1e-12f)));
    __syncthreads();

    if (t < S) {
        int r = t;
        float s = 0.f, mn = INFINITY;
        for (int q = 0; q < S; ++q) {
            float e = Et[r][q];
            s += e;
            mn = fminf(mn, e);
        }
        size_t o = ((size_t)i * B + j) * S + r;
        rowsum[o] = s;
        rowmin[o] = mn;
    } else if (t < 2 * S && i != j) {
        int c = t - S;
        float s = 0.f, mn = INFINITY;
        for (int p = 0; p < S; ++p) {
            float e = Et[p][c];
            s += e;
            mn = fminf(mn, e);
        }
        size_t o = ((size_t)j * B + i) * S + c;
        rowsum[o] = s;
        rowmin[o] = mn;
    }
}

// ---------------------------------------------------------------------------
// K3: per unordered pair (i < j): build
//   a[p] = rowmin[i][j][p] / (rowsum[i][i][p] + rowsum[i][j][p])
//   c[q] = rowmin[j][i][q] / (rowsum[j][i][q] + rowsum[j][j][q])
// take 3rd and 6th largest of each (stable rank over 32 values), then
//   v_same = max(a6, c6), v_diff = min(a3, c3)
//   Dmat[i][j] = Dmat[j][i] = (tgt[i]==tgt[j]) ? v_same : v_diff
// One 64-thread block per pair: lanes 0-31 -> a, lanes 32-63 -> c.
// ---------------------------------------------------------------------------
__global__ __launch_bounds__(64) void pair_select_kernel(const float* __restrict__ rowsum,
                                                         const float* __restrict__ rowmin,
                                                         const int* __restrict__ tgt,
                                                         float* __restrict__ Dmat) {
    int j = blockIdx.x;
    int i = blockIdx.y;
    if (i >= j) return;

    __shared__ float sv[64];
    __shared__ float ksel[2][2];  // [half][0 -> rank2 (3rd largest), 1 -> rank5 (6th largest)]

    int t = threadIdx.x;
    float v;
    if (t < 32) {
        int p = t;
        size_t oij = ((size_t)i * B + j) * S + p;
        size_t oii = ((size_t)i * B + i) * S + p;
        v = rowmin[oij] / (rowsum[oii] + rowsum[oij]);
    } else {
        int q = t - 32;
        size_t oji = ((size_t)j * B + i) * S + q;
        size_t ojj = ((size_t)j * B + j) * S + q;
        v = rowmin[oji] / (rowsum[ojj] + rowsum[oji]);
    }
    sv[t] = v;
    __syncthreads();

    int base = t & 32;
    int rank = 0;
    for (int m = 0; m < 32; ++m) {
        float vm = sv[base + m];
        if (vm > v || (vm == v && (base + m) < t)) ++rank;
    }
    if (rank == 2) ksel[t >> 5][0] = v;
    if (rank == 5) ksel[t >> 5][1] = v;
    __syncthreads();

    if (t == 0) {
        float v_diff = fminf(ksel[0][0], ksel[1][0]);
        float v_same = fmaxf(ksel[0][1], ksel[1][1]);
        float val = (tgt[i] == tgt[j]) ? v_same : v_diff;
        Dmat[i * B + j] = val;
        Dmat[j * B + i] = val;
    }
}

// ---------------------------------------------------------------------------
// K4: hardest positive / hardest negative per row + mean of margin ranking loss.
// Single block of 128 threads; diag treated as 0 with mask=true (reference).
// ---------------------------------------------------------------------------
__global__ __launch_bounds__(128) void final_kernel(const float* __restrict__ Dmat,
                                                    const int* __restrict__ tgt,
                                                    float* __restrict__ out) {
    int i = threadIdx.x;
    int ti = tgt[i];
    float ap = -INFINITY, an = INFINITY;
    for (int jj = 0; jj < B; ++jj) {
        float v = (jj == i) ? 0.f : Dmat[i * B + jj];
        if (tgt[jj] == ti) ap = fmaxf(ap, v);
        else an = fminf(an, v);
    }
    float term = ap - an + MARGINF;
    term = term > 0.f ? term : 0.f;

    __shared__ float red[128];
    red[i] = term;
    __syncthreads();
    for (int off = 64; off >= 1; off >>= 1) {
        if (i < off) red[i] += red[i + off];
        __syncthreads();
    }
    if (i == 0) out[0] = red[0] / (float)B;
}

// ---------------------------------------------------------------------------
extern "C" void kernel_launch(void* const* d_in, const int* in_sizes, int n_in,
                              void* d_out, int out_size, void* d_ws, size_t ws_size,
                              hipStream_t stream) {
    const float* X = (const float*)d_in[0];   // (128, 32, 128) f32
    const int* tgt = (const int*)d_in[1];     // (128,) int
    float* out = (float*)d_out;

    // workspace layout (floats): total ~6.4 MB
    float* ws = (float*)d_ws;
    float* Xn = ws;                          // NV*Dm   = 524288
    float* sqv = Xn + (size_t)NV * Dm;       // NV      = 4096
    float* rowsum = sqv + NV;                // B*B*S   = 524288
    float* rowmin = rowsum + (size_t)B * B * S;  // 524288
    float* Dmat = rowmin + (size_t)B * B * S;    // 16384

    norm_kernel<<<NV, 64, 0, stream>>>(X, Xn, sqv);

    dim3 grid2(B, B);
    pair_block_kernel<<<grid2, 256, 0, stream>>>(Xn, sqv, rowsum, rowmin);

    dim3 grid3(B, B);
    pair_select_kernel<<<grid3, 64, 0, stream>>>(rowsum, rowmin, tgt, Dmat);

    final_kernel<<<1, 128, 0, stream>>>(Dmat, tgt, out);
}

// Round 5
// 124.662 us; speedup vs baseline: 2.8195x; 2.8195x over previous
//
#include <hip/hip_runtime.h>
#include <math.h>

#define B 128
#define S 32
#define Dm 128
#define NV (B * S)
#define MARGINF 0.3f

// ---------------------------------------------------------------------------
// K1: L2-normalize each of the 4096 vectors (dim 128); also store sq = sum(x^2)
// after normalization (matches reference, which recomputes sq on normalized x).
// ---------------------------------------------------------------------------
__global__ __launch_bounds__(64) void norm_kernel(const float* __restrict__ X,
                                                  float* __restrict__ Xn,
                                                  float* __restrict__ sqv) {
    int v = blockIdx.x;
    int l = threadIdx.x;
    const float* xr = X + (size_t)v * Dm;
    float a = xr[l];
    float b = xr[l + 64];
    float ss = a * a + b * b;
    for (int off = 32; off >= 1; off >>= 1) ss += __shfl_down(ss, off);
    ss = __shfl(ss, 0);
    float nrm = sqrtf(ss);
    float inv = 1.0f / fmaxf(nrm, 1e-12f);
    Xn[(size_t)v * Dm + l] = a * inv;
    Xn[(size_t)v * Dm + l + 64] = b * inv;
    if (l == 0) sqv[v] = ss * inv * inv;
}

// ---------------------------------------------------------------------------
// K2: block (jg, i) handles pairs (i, j) for j in [4*jg, 4*jg+3], j >= i.
// Stages panel i + 4 j-panels into LDS with XOR-swizzled float4 slots
// (slot = kk ^ (row>>2)) so the 4x4-tiled gram reads are bank-conflict-free.
// One wave per pair; lane l computes a 4x4 tile (pg = l>>3 row group,
// qg = l&7 col group). Row/col sum+min of E = exp(dist) are reduced with
// shfl_xor butterflies and written as float4:
//   rowsum[i][j][p], rowmin[i][j][p]   (row stats of block (i,j))
//   rowsum[j][i][q], rowmin[j][i][q]   (col stats, i != j)
// ---------------------------------------------------------------------------
__global__ __launch_bounds__(256) void pair_block_kernel(const float* __restrict__ Xn,
                                                         const float* __restrict__ sqv,
                                                         float* __restrict__ rowsum,
                                                         float* __restrict__ rowmin) {
    int jg = blockIdx.x;       // 0..31
    int i  = blockIdx.y;       // 0..127
    int jbase = jg * 4;
    if (i > jbase + 3) return;  // uniform early-exit: no j >= i in this group

    extern __shared__ float4 lds[];   // 5 * 1024 float4 = 80 KB
    float4* Pi  = lds;                // panel i  (32 rows x 32 float4, swizzled)
    float4* Pj0 = lds + 1024;         // 4 j-panels

    int t = threadIdx.x;

    // Stage panel i (1024 float4s) with swizzle.
    {
        const float4* src = (const float4*)(Xn + (size_t)i * S * Dm);
        for (int k = t; k < 1024; k += 256) {
            int row = k >> 5, kk = k & 31;
            Pi[row * 32 + (kk ^ (row >> 2))] = src[k];
        }
        // Stage 4 consecutive j-panels (4096 float4s, contiguous source).
        const float4* srcj = (const float4*)(Xn + (size_t)jbase * S * Dm);
        for (int k = t; k < 4096; k += 256) {
            int grow = k >> 5, kk = k & 31;     // grow 0..127
            int panel = grow >> 5, row = grow & 31;
            Pj0[panel * 1024 + row * 32 + (kk ^ (row >> 2))] = srcj[k];
        }
    }
    __syncthreads();

    int w = t >> 6;            // wave id -> which j
    int j = jbase + w;
    if (j < i) return;         // idle waves (no further barriers)

    const float4* Pj = Pj0 + w * 1024;
    int l  = t & 63;
    int pg = l >> 3;           // row group: rows pg*4 .. pg*4+3
    int qg = l & 7;            // col group: cols qg*4 .. qg*4+3

    float4 acc[4][4];
#pragma unroll
    for (int a = 0; a < 4; ++a)
#pragma unroll
        for (int b = 0; b < 4; ++b) acc[a][b] = make_float4(0.f, 0.f, 0.f, 0.f);

    int pbase = pg * 128;      // (pg*4)*32
    int qbase = qg * 128;

#pragma unroll 4
    for (int kk = 0; kk < 32; ++kk) {
        int si_ = kk ^ pg;
        int sj_ = kk ^ qg;
        float4 ai[4], bj[4];
#pragma unroll
        for (int r = 0; r < 4; ++r) ai[r] = Pi[pbase + r * 32 + si_];
#pragma unroll
        for (int r = 0; r < 4; ++r) bj[r] = Pj[qbase + r * 32 + sj_];
#pragma unroll
        for (int a = 0; a < 4; ++a)
#pragma unroll
            for (int b = 0; b < 4; ++b) {
                acc[a][b].x += ai[a].x * bj[b].x;
                acc[a][b].y += ai[a].y * bj[b].y;
                acc[a][b].z += ai[a].z * bj[b].z;
                acc[a][b].w += ai[a].w * bj[b].w;
            }
    }

    float4 siv = *(const float4*)(sqv + i * S + pg * 4);
    float4 sjv = *(const float4*)(sqv + j * S + qg * 4);
    float sia[4] = {siv.x, siv.y, siv.z, siv.w};
    float sjb[4] = {sjv.x, sjv.y, sjv.z, sjv.w};

    float rs[4], rm[4], cs[4], cm[4];
#pragma unroll
    for (int a = 0; a < 4; ++a) { rs[a] = 0.f; rm[a] = INFINITY; }
#pragma unroll
    for (int b = 0; b < 4; ++b) { cs[b] = 0.f; cm[b] = INFINITY; }

#pragma unroll
    for (int a = 0; a < 4; ++a)
#pragma unroll
        for (int b = 0; b < 4; ++b) {
            float dot = acc[a][b].x + acc[a][b].y + acc[a][b].z + acc[a][b].w;
            float d2 = sia[a] + sjb[b] - 2.f * dot;
            float dist = sqrtf(fmaxf(d2, 1e-12f));
            float ev = expf(dist);
            rs[a] += ev; rm[a] = fminf(rm[a], ev);
            cs[b] += ev; cm[b] = fminf(cm[b], ev);
        }

    // Row stats: reduce over the 8 q-groups (lanes differing in bits 0..2).
#pragma unroll
    for (int m = 1; m <= 4; m <<= 1)
#pragma unroll
        for (int a = 0; a < 4; ++a) {
            rs[a] += __shfl_xor(rs[a], m);
            rm[a] = fminf(rm[a], __shfl_xor(rm[a], m));
        }
    // Col stats: reduce over the 8 p-groups (lanes differing in bits 3..5).
#pragma unroll
    for (int m = 8; m <= 32; m <<= 1)
#pragma unroll
        for (int b = 0; b < 4; ++b) {
            cs[b] += __shfl_xor(cs[b], m);
            cm[b] = fminf(cm[b], __shfl_xor(cm[b], m));
        }

    if (qg == 0) {
        size_t o = ((size_t)i * B + j) * S + pg * 4;
        *(float4*)(rowsum + o) = make_float4(rs[0], rs[1], rs[2], rs[3]);
        *(float4*)(rowmin + o) = make_float4(rm[0], rm[1], rm[2], rm[3]);
    }
    if (pg == 0 && i != j) {
        size_t o = ((size_t)j * B + i) * S + qg * 4;
        *(float4*)(rowsum + o) = make_float4(cs[0], cs[1], cs[2], cs[3]);
        *(float4*)(rowmin + o) = make_float4(cm[0], cm[1], cm[2], cm[3]);
    }
}

// ---------------------------------------------------------------------------
// K3: per unordered pair (i < j): a[p], c[q], rank-select 3rd/6th largest,
// write symmetric D.
// ---------------------------------------------------------------------------
__global__ __launch_bounds__(64) void pair_select_kernel(const float* __restrict__ rowsum,
                                                         const float* __restrict__ rowmin,
                                                         const int* __restrict__ tgt,
                                                         float* __restrict__ Dmat) {
    int j = blockIdx.x;
    int i = blockIdx.y;
    if (i >= j) return;

    __shared__ float sv[64];
    __shared__ float ksel[2][2];

    int t = threadIdx.x;
    float v;
    if (t < 32) {
        int p = t;
        size_t oij = ((size_t)i * B + j) * S + p;
        size_t oii = ((size_t)i * B + i) * S + p;
        v = rowmin[oij] / (rowsum[oii] + rowsum[oij]);
    } else {
        int q = t - 32;
        size_t oji = ((size_t)j * B + i) * S + q;
        size_t ojj = ((size_t)j * B + j) * S + q;
        v = rowmin[oji] / (rowsum[ojj] + rowsum[oji]);
    }
    sv[t] = v;
    __syncthreads();

    int base = t & 32;
    int rank = 0;
    for (int m = 0; m < 32; ++m) {
        float vm = sv[base + m];
        if (vm > v || (vm == v && (base + m) < t)) ++rank;
    }
    if (rank == 2) ksel[t >> 5][0] = v;
    if (rank == 5) ksel[t >> 5][1] = v;
    __syncthreads();

    if (t == 0) {
        float v_diff = fminf(ksel[0][0], ksel[1][0]);
        float v_same = fmaxf(ksel[0][1], ksel[1][1]);
        float val = (tgt[i] == tgt[j]) ? v_same : v_diff;
        Dmat[i * B + j] = val;
        Dmat[j * B + i] = val;
    }
}

// ---------------------------------------------------------------------------
// K4: hardest positive / hardest negative per row + mean margin-ranking loss.
// ---------------------------------------------------------------------------
__global__ __launch_bounds__(128) void final_kernel(const float* __restrict__ Dmat,
                                                    const int* __restrict__ tgt,
                                                    float* __restrict__ out) {
    int i = threadIdx.x;
    int ti = tgt[i];
    float ap = -INFINITY, an = INFINITY;
    for (int jj = 0; jj < B; ++jj) {
        float v = (jj == i) ? 0.f : Dmat[i * B + jj];
        if (tgt[jj] == ti) ap = fmaxf(ap, v);
        else an = fminf(an, v);
    }
    float term = ap - an + MARGINF;
    term = term > 0.f ? term : 0.f;

    __shared__ float red[128];
    red[i] = term;
    __syncthreads();
    for (int off = 64; off >= 1; off >>= 1) {
        if (i < off) red[i] += red[i + off];
        __syncthreads();
    }
    if (i == 0) out[0] = red[0] / (float)B;
}

// ---------------------------------------------------------------------------
extern "C" void kernel_launch(void* const* d_in, const int* in_sizes, int n_in,
                              void* d_out, int out_size, void* d_ws, size_t ws_size,
                              hipStream_t stream) {
    const float* X = (const float*)d_in[0];   // (128, 32, 128) f32
    const int* tgt = (const int*)d_in[1];     // (128,) int
    float* out = (float*)d_out;

    float* ws = (float*)d_ws;
    float* Xn = ws;                               // NV*Dm   = 524288
    float* sqv = Xn + (size_t)NV * Dm;            // NV      = 4096
    float* rowsum = sqv + NV;                     // B*B*S   = 524288
    float* rowmin = rowsum + (size_t)B * B * S;   // 524288
    float* Dmat = rowmin + (size_t)B * B * S;     // 16384

    norm_kernel<<<NV, 64, 0, stream>>>(X, Xn, sqv);

    dim3 grid2(S, B);  // (jg, i): 32 j-groups x 128 i
    pair_block_kernel<<<grid2, 256, 5 * 1024 * sizeof(float4), stream>>>(Xn, sqv, rowsum, rowmin);

    dim3 grid3(B, B);
    pair_select_kernel<<<grid3, 64, 0, stream>>>(rowsum, rowmin, tgt, Dmat);

    final_kernel<<<1, 128, 0, stream>>>(Dmat, tgt, out);
}

// Round 6
// 68.795 us; speedup vs baseline: 5.1092x; 1.8121x over previous
//
#include <hip/hip_runtime.h>
#include <math.h>

#define B 128
#define S 32
#define Dm 128
#define NV (B * S)
#define MARGINF 0.3f

typedef __attribute__((ext_vector_type(8))) short short8;
typedef __attribute__((ext_vector_type(16))) float f32x16;

// RNE f32 -> bf16 (finite inputs only)
__device__ inline unsigned short f2bf(float f) {
    unsigned u = __float_as_uint(f);
    unsigned r = u + 0x7FFF + ((u >> 16) & 1);
    return (unsigned short)(r >> 16);
}

// ---------------------------------------------------------------------------
// K1: L2-normalize each vector; emit z = [hi(128) | lo(128)] bf16 row (256)
// such that hi+lo reproduces the normalized f32 to ~2^-17, plus sqv = |xn|^2.
// ---------------------------------------------------------------------------
__global__ __launch_bounds__(64) void norm_kernel(const float* __restrict__ X,
                                                  unsigned short* __restrict__ Zn,
                                                  float* __restrict__ sqv) {
    int v = blockIdx.x;
    int l = threadIdx.x;
    const float* xr = X + (size_t)v * Dm;
    float a = xr[l];
    float b = xr[l + 64];
    float ss = a * a + b * b;
    for (int off = 32; off >= 1; off >>= 1) ss += __shfl_down(ss, off);
    ss = __shfl(ss, 0);
    float inv = 1.0f / fmaxf(sqrtf(ss), 1e-12f);
    float na = a * inv, nb = b * inv;

    unsigned short ha = f2bf(na), hb = f2bf(nb);
    float la = na - __uint_as_float(((unsigned)ha) << 16);
    float lb = nb - __uint_as_float(((unsigned)hb) << 16);

    unsigned short* zr = Zn + (size_t)v * 256;
    zr[l]        = ha;
    zr[64 + l]   = hb;
    zr[128 + l]  = f2bf(la);
    zr[192 + l]  = f2bf(lb);
    if (l == 0) sqv[v] = ss * inv * inv;
}

// ---------------------------------------------------------------------------
// K2: triangular block t -> (jg, i), i <= 4*jg+3. Stages panel i + 4 j-panels
// (bf16 z-rows, 512 B each) into LDS with 16B-slot XOR swizzle
// (slot ^= row&7, G4 idiom). One wave per pair (i, j=4jg+w), j >= i.
// Gram via 16x mfma_f32_32x32x16_bf16 over K=256 (hi|lo concat => full f32
// product). Epilogue: E = exp(sqrt(clip(sq_i+sq_j-2dot))), row/col sum+min
// reduced in-register (shfl_xor), written to rowsum/rowmin[(i,j)] / [(j,i)].
// ---------------------------------------------------------------------------
__global__ __launch_bounds__(256) void pair_block_kernel(const unsigned short* __restrict__ Zn,
                                                         const float* __restrict__ sqv,
                                                         float* __restrict__ rowsum,
                                                         float* __restrict__ rowmin) {
    // unrank t -> (jg, i): start(jg) = 2*jg^2 + 2*jg
    int t0 = blockIdx.x;
    int jg = (int)((sqrtf(2.f * (float)t0 + 1.f) - 1.f) * 0.5f);
    while (jg > 0 && t0 < 2 * jg * jg + 2 * jg) --jg;
    while (t0 >= 2 * (jg + 1) * (jg + 1) + 2 * (jg + 1)) ++jg;
    int i = t0 - (2 * jg * jg + 2 * jg);   // 0 .. 4*jg+3
    int jbase = jg * 4;

    extern __shared__ unsigned short lds[];   // 5 panels * 8192 ushort = 80 KB

    int t = threadIdx.x;

    // Stage 5 panels: 5*1024 16B-chunks. chunk c: row=c>>5, slot=c&31.
    for (int k = t; k < 5 * 1024; k += 256) {
        int panel = k >> 10;
        int c = k & 1023;
        int row = c >> 5, slot = c & 31;
        int vec = (panel == 0) ? i : (jbase + panel - 1);
        const short8 src = *(const short8*)(Zn + (size_t)vec * 256 + slot * 8);
        *(short8*)(lds + panel * 8192 + row * 256 + ((slot ^ (row & 7)) << 3)) = src;
    }
    __syncthreads();

    int w = t >> 6;
    int j = jbase + w;
    if (j < i) return;          // no further barriers

    const unsigned short* Pi = lds;
    const unsigned short* Pj = lds + (w + 1) * 8192;
    int l = t & 63;
    int lq = l & 31;            // spatial lane (A-row / B-col)
    int kh = l >> 5;            // k-half within a 16-wide K step
    int sx = lq & 7;            // swizzle key

    f32x16 acc;
#pragma unroll
    for (int r = 0; r < 16; ++r) acc[r] = 0.f;

#pragma unroll
    for (int ks = 0; ks < 16; ++ks) {
        int off = lq * 256 + ((((ks << 1) | kh) ^ sx) << 3);
        short8 av = *(const short8*)(Pi + off);
        short8 bv = *(const short8*)(Pj + off);
        acc = __builtin_amdgcn_mfma_f32_32x32x16_bf16(av, bv, acc, 0, 0, 0);
    }

    // ---- epilogue ----
    float sqj = sqv[j * S + lq];
    float ev[16];
#pragma unroll
    for (int r = 0; r < 16; ++r) {
        int p = (r & 3) + 8 * (r >> 2) + 4 * kh;
        float d2 = sqv[i * S + p] + sqj - 2.f * acc[r];
        ev[r] = expf(sqrtf(fmaxf(d2, 1e-12f)));
    }

    // col stats (fixed q = lq, reduce over the 16 regs + the half swap)
    float csum = 0.f, cmin = INFINITY;
#pragma unroll
    for (int r = 0; r < 16; ++r) { csum += ev[r]; cmin = fminf(cmin, ev[r]); }
    csum += __shfl_xor(csum, 32);
    cmin = fminf(cmin, __shfl_xor(cmin, 32));
    if (i != j && kh == 0) {
        size_t o = ((size_t)j * B + i) * S + lq;
        rowsum[o] = csum;
        rowmin[o] = cmin;
    }

    // row stats (fixed p per reg, reduce over q = lanes within each half)
    float rsum[16], rmin[16];
#pragma unroll
    for (int r = 0; r < 16; ++r) { rsum[r] = ev[r]; rmin[r] = ev[r]; }
#pragma unroll
    for (int m = 1; m <= 16; m <<= 1)
#pragma unroll
        for (int r = 0; r < 16; ++r) {
            rsum[r] += __shfl_xor(rsum[r], m);
            rmin[r] = fminf(rmin[r], __shfl_xor(rmin[r], m));
        }
    if (lq == 0) {
        size_t ob = ((size_t)i * B + j) * S;
#pragma unroll
        for (int r = 0; r < 16; ++r) {
            int p = (r & 3) + 8 * (r >> 2) + 4 * kh;
            rowsum[ob + p] = rsum[r];
            rowmin[ob + p] = rmin[r];
        }
    }
}

// ---------------------------------------------------------------------------
// K3: triangular 1D grid over pairs (i < j): a[p], c[q], rank-select 3rd/6th
// largest, write symmetric D.
// ---------------------------------------------------------------------------
__global__ __launch_bounds__(64) void pair_select_kernel(const float* __restrict__ rowsum,
                                                         const float* __restrict__ rowmin,
                                                         const int* __restrict__ tgt,
                                                         float* __restrict__ Dmat) {
    // unrank: start(i) = i*(B-1) - i*(i-1)/2
    int tp = blockIdx.x;
    float A = 2.f * (B - 1) + 1.f;
    int i = (int)floorf((A - sqrtf(A * A - 8.f * (float)tp)) * 0.5f);
    if (i < 0) i = 0;
    if (i > B - 2) i = B - 2;
    while (i > 0 && tp < i * (B - 1) - i * (i - 1) / 2) --i;
    while (tp >= (i + 1) * (B - 1) - (i + 1) * i / 2) ++i;
    int j = i + 1 + (tp - (i * (B - 1) - i * (i - 1) / 2));

    __shared__ float sv[64];
    __shared__ float ksel[2][2];

    int t = threadIdx.x;
    float v;
    if (t < 32) {
        int p = t;
        size_t oij = ((size_t)i * B + j) * S + p;
        size_t oii = ((size_t)i * B + i) * S + p;
        v = rowmin[oij] / (rowsum[oii] + rowsum[oij]);
    } else {
        int q = t - 32;
        size_t oji = ((size_t)j * B + i) * S + q;
        size_t ojj = ((size_t)j * B + j) * S + q;
        v = rowmin[oji] / (rowsum[ojj] + rowsum[oji]);
    }
    sv[t] = v;
    __syncthreads();

    int base = t & 32;
    int rank = 0;
    for (int m = 0; m < 32; ++m) {
        float vm = sv[base + m];
        if (vm > v || (vm == v && (base + m) < t)) ++rank;
    }
    if (rank == 2) ksel[t >> 5][0] = v;
    if (rank == 5) ksel[t >> 5][1] = v;
    __syncthreads();

    if (t == 0) {
        float v_diff = fminf(ksel[0][0], ksel[1][0]);
        float v_same = fmaxf(ksel[0][1], ksel[1][1]);
        float val = (tgt[i] == tgt[j]) ? v_same : v_diff;
        Dmat[i * B + j] = val;
        Dmat[j * B + i] = val;
    }
}

// ---------------------------------------------------------------------------
// K4: hardest positive / hardest negative per row + mean margin-ranking loss.
// ---------------------------------------------------------------------------
__global__ __launch_bounds__(128) void final_kernel(const float* __restrict__ Dmat,
                                                    const int* __restrict__ tgt,
                                                    float* __restrict__ out) {
    int i = threadIdx.x;
    int ti = tgt[i];
    float ap = -INFINITY, an = INFINITY;
    for (int jj = 0; jj < B; ++jj) {
        float v = (jj == i) ? 0.f : Dmat[i * B + jj];
        if (tgt[jj] == ti) ap = fmaxf(ap, v);
        else an = fminf(an, v);
    }
    float term = ap - an + MARGINF;
    term = term > 0.f ? term : 0.f;

    __shared__ float red[128];
    red[i] = term;
    __syncthreads();
    for (int off = 64; off >= 1; off >>= 1) {
        if (i < off) red[i] += red[i + off];
        __syncthreads();
    }
    if (i == 0) out[0] = red[0] / (float)B;
}

// ---------------------------------------------------------------------------
extern "C" void kernel_launch(void* const* d_in, const int* in_sizes, int n_in,
                              void* d_out, int out_size, void* d_ws, size_t ws_size,
                              hipStream_t stream) {
    const float* X = (const float*)d_in[0];   // (128, 32, 128) f32
    const int* tgt = (const int*)d_in[1];     // (128,) int
    float* out = (float*)d_out;

    // workspace: Zn bf16 2MB | sqv 16KB | rowsum 2MB | rowmin 2MB | Dmat 64KB
    unsigned short* Zn = (unsigned short*)d_ws;
    float* sqv = (float*)(Zn + (size_t)NV * 256);
    float* rowsum = sqv + NV;
    float* rowmin = rowsum + (size_t)B * B * S;
    float* Dmat = rowmin + (size_t)B * B * S;

    norm_kernel<<<NV, 64, 0, stream>>>(X, Zn, sqv);

    int nblk2 = 2112;  // sum over jg of (4*jg+4)
    pair_block_kernel<<<nblk2, 256, 5 * 8192 * sizeof(unsigned short), stream>>>(Zn, sqv, rowsum, rowmin);

    int npair = B * (B - 1) / 2;  // 8128
    pair_select_kernel<<<npair, 64, 0, stream>>>(rowsum, rowmin, tgt, Dmat);

    final_kernel<<<1, 128, 0, stream>>>(Dmat, tgt, out);
}

// Round 7
// 64.642 us; speedup vs baseline: 5.4374x; 1.0642x over previous
//
#include <hip/hip_runtime.h>
#include <math.h>

#define B 128
#define S 32
#define Dm 128
#define NV (B * S)
#define MARGINF 0.3f

typedef __attribute__((ext_vector_type(8))) short short8;
typedef __attribute__((ext_vector_type(16))) float f32x16;

#define GLOBAL_AS __attribute__((address_space(1)))
#define LDS_AS __attribute__((address_space(3)))

// RNE f32 -> bf16 (finite inputs only)
__device__ inline unsigned short f2bf(float f) {
    unsigned u = __float_as_uint(f);
    unsigned r = u + 0x7FFF + ((u >> 16) & 1);
    return (unsigned short)(r >> 16);
}

// ---------------------------------------------------------------------------
// K1: L2-normalize each vector; emit z = [hi(128) | lo(128)] bf16 row (256)
// such that hi+lo reproduces the normalized f32 to ~2^-17, plus sqv = |xn|^2.
// ---------------------------------------------------------------------------
__global__ __launch_bounds__(64) void norm_kernel(const float* __restrict__ X,
                                                  unsigned short* __restrict__ Zn,
                                                  float* __restrict__ sqv) {
    int v = blockIdx.x;
    int l = threadIdx.x;
    const float* xr = X + (size_t)v * Dm;
    float a = xr[l];
    float b = xr[l + 64];
    float ss = a * a + b * b;
    for (int off = 32; off >= 1; off >>= 1) ss += __shfl_down(ss, off);
    ss = __shfl(ss, 0);
    float inv = 1.0f / fmaxf(sqrtf(ss), 1e-12f);
    float na = a * inv, nb = b * inv;

    unsigned short ha = f2bf(na), hb = f2bf(nb);
    float la = na - __uint_as_float(((unsigned)ha) << 16);
    float lb = nb - __uint_as_float(((unsigned)hb) << 16);

    unsigned short* zr = Zn + (size_t)v * 256;
    zr[l]        = ha;
    zr[64 + l]   = hb;
    zr[128 + l]  = f2bf(la);
    zr[192 + l]  = f2bf(lb);
    if (l == 0) sqv[v] = ss * inv * inv;
}

// ---------------------------------------------------------------------------
// K2: triangular block t -> (jg, i), i <= 4*jg+3. Stages panel i + 4 j-panels
// (bf16 z-rows, 512 B each) into LDS via global_load_lds width=16:
// LDS dest is LINEAR (wave-uniform base + lane*16); the 16B-slot XOR swizzle
// (slot ^= row&7) is applied to the per-lane GLOBAL source address, and the
// same involution on the ds_read side. One wave per pair (i, j=4jg+w), j>=i.
// Gram via 16x mfma_f32_32x32x16_bf16 over K=256 (hi|lo concat => full f32
// product), split into 2 accumulator chains. Epilogue: E = exp(sqrt(clip(
// sq_i+sq_j-2dot))), row/col sum+min reduced in-register (shfl), sqv row
// redistributed by __shfl instead of 16 scattered loads.
// ---------------------------------------------------------------------------
__global__ __launch_bounds__(256) void pair_block_kernel(const unsigned short* __restrict__ Zn,
                                                         const float* __restrict__ sqv,
                                                         float* __restrict__ rowsum,
                                                         float* __restrict__ rowmin) {
    // unrank t -> (jg, i): start(jg) = 2*jg^2 + 2*jg
    int t0 = blockIdx.x;
    int jg = (int)((sqrtf(2.f * (float)t0 + 1.f) - 1.f) * 0.5f);
    while (jg > 0 && t0 < 2 * jg * jg + 2 * jg) --jg;
    while (t0 >= 2 * (jg + 1) * (jg + 1) + 2 * (jg + 1)) ++jg;
    int i = t0 - (2 * jg * jg + 2 * jg);   // 0 .. 4*jg+3
    int jbase = jg * 4;

    extern __shared__ unsigned short lds[];   // 5 panels * 8192 ushort = 80 KB

    int t = threadIdx.x;
    int w = t >> 6;
    int lane = t & 63;

    // ---- staging: 80 segments of 1024 B; wave w owns segs [w*20, w*20+20) ----
    // Linear LDS chunk L = seg*64 + lane; panel = L>>10; within-panel:
    // row = (L>>5)&31, slot' = lane&31. Source chunk = (row, slot'^(row&7)).
    {
        int slotp = lane & 31;
        int rlo = lane >> 5;                       // +0 or +1 row within segment
#pragma unroll
        for (int k = 0; k < 20; ++k) {
            int seg = w * 20 + k;                  // 0..79 (uniform per wave)
            int panel = seg >> 4;                  // 16 segs per panel
            int row = ((seg & 15) << 1) + rlo;     // 0..31
            int vec = (panel == 0) ? i : (jbase + panel - 1);
            const unsigned short* gsrc =
                Zn + (((size_t)vec * 32 + row) << 8) + ((slotp ^ (row & 7)) << 3);
            unsigned short* ldst = lds + seg * 512;   // wave-uniform
            __builtin_amdgcn_global_load_lds((const GLOBAL_AS void*)(const void*)gsrc,
                                             (LDS_AS void*)(void*)ldst, 16, 0, 0);
        }
    }
    __syncthreads();   // compiler drains vmcnt(0) before the barrier

    int j = jbase + w;
    if (j < i) return;          // no further barriers

    const unsigned short* Pi = lds;
    const unsigned short* Pj = lds + (w + 1) * 8192;
    int lq = lane & 31;         // spatial lane (A-row / B-col)
    int kh = lane >> 5;         // k-half within a 16-wide K step
    int sx = lq & 7;            // swizzle key

    // prefetch sqv rows (1 value per lane; redistribute later via shfl)
    float sqi = sqv[i * S + lq];
    float sqj = sqv[j * S + lq];

    f32x16 acc0, acc1;
#pragma unroll
    for (int r = 0; r < 16; ++r) { acc0[r] = 0.f; acc1[r] = 0.f; }

#pragma unroll
    for (int ks = 0; ks < 16; ks += 2) {
        int off0 = lq * 256 + ((((ks << 1) | kh) ^ sx) << 3);
        int off1 = lq * 256 + (((((ks + 1) << 1) | kh) ^ sx) << 3);
        short8 av0 = *(const short8*)(Pi + off0);
        short8 bv0 = *(const short8*)(Pj + off0);
        short8 av1 = *(const short8*)(Pi + off1);
        short8 bv1 = *(const short8*)(Pj + off1);
        acc0 = __builtin_amdgcn_mfma_f32_32x32x16_bf16(av0, bv0, acc0, 0, 0, 0);
        acc1 = __builtin_amdgcn_mfma_f32_32x32x16_bf16(av1, bv1, acc1, 0, 0, 0);
    }

    // ---- epilogue ----
    float ev[16];
#pragma unroll
    for (int r = 0; r < 16; ++r) {
        int p = (r & 3) + 8 * (r >> 2) + 4 * kh;
        float sqip = __shfl(sqi, p);               // lanes 0..31 hold sqv_i[0..31]
        float d2 = sqip + sqj - 2.f * (acc0[r] + acc1[r]);
        ev[r] = expf(sqrtf(fmaxf(d2, 1e-12f)));
    }

    // col stats (fixed q = lq, reduce over the 16 regs + the half swap)
    float csum = 0.f, cmin = INFINITY;
#pragma unroll
    for (int r = 0; r < 16; ++r) { csum += ev[r]; cmin = fminf(cmin, ev[r]); }
    csum += __shfl_xor(csum, 32);
    cmin = fminf(cmin, __shfl_xor(cmin, 32));
    if (i != j && kh == 0) {
        size_t o = ((size_t)j * B + i) * S + lq;
        rowsum[o] = csum;
        rowmin[o] = cmin;
    }

    // row stats (fixed p per reg, reduce over q = lanes within each half)
    float rsum[16], rmin[16];
#pragma unroll
    for (int r = 0; r < 16; ++r) { rsum[r] = ev[r]; rmin[r] = ev[r]; }
#pragma unroll
    for (int m = 1; m <= 16; m <<= 1)
#pragma unroll
        for (int r = 0; r < 16; ++r) {
            rsum[r] += __shfl_xor(rsum[r], m);
            rmin[r] = fminf(rmin[r], __shfl_xor(rmin[r], m));
        }
    if (lq == 0) {
        size_t ob = ((size_t)i * B + j) * S;
#pragma unroll
        for (int r = 0; r < 16; ++r) {
            int p = (r & 3) + 8 * (r >> 2) + 4 * kh;
            rowsum[ob + p] = rsum[r];
            rowmin[ob + p] = rmin[r];
        }
    }
}

// ---------------------------------------------------------------------------
// K3: triangular 1D grid over pairs (i < j): a[p], c[q], rank-select 3rd/6th
// largest, write symmetric D.
// ---------------------------------------------------------------------------
__global__ __launch_bounds__(64) void pair_select_kernel(const float* __restrict__ rowsum,
                                                         const float* __restrict__ rowmin,
                                                         const int* __restrict__ tgt,
                                                         float* __restrict__ Dmat) {
    // unrank: start(i) = i*(B-1) - i*(i-1)/2
    int tp = blockIdx.x;
    float A = 2.f * (B - 1) + 1.f;
    int i = (int)floorf((A - sqrtf(A * A - 8.f * (float)tp)) * 0.5f);
    if (i < 0) i = 0;
    if (i > B - 2) i = B - 2;
    while (i > 0 && tp < i * (B - 1) - i * (i - 1) / 2) --i;
    while (tp >= (i + 1) * (B - 1) - (i + 1) * i / 2) ++i;
    int j = i + 1 + (tp - (i * (B - 1) - i * (i - 1) / 2));

    __shared__ float sv[64];
    __shared__ float ksel[2][2];

    int t = threadIdx.x;
    float v;
    if (t < 32) {
        int p = t;
        size_t oij = ((size_t)i * B + j) * S + p;
        size_t oii = ((size_t)i * B + i) * S + p;
        v = rowmin[oij] / (rowsum[oii] + rowsum[oij]);
    } else {
        int q = t - 32;
        size_t oji = ((size_t)j * B + i) * S + q;
        size_t ojj = ((size_t)j * B + j) * S + q;
        v = rowmin[oji] / (rowsum[ojj] + rowsum[oji]);
    }
    sv[t] = v;
    __syncthreads();

    int base = t & 32;
    int rank = 0;
    for (int m = 0; m < 32; ++m) {
        float vm = sv[base + m];
        if (vm > v || (vm == v && (base + m) < t)) ++rank;
    }
    if (rank == 2) ksel[t >> 5][0] = v;
    if (rank == 5) ksel[t >> 5][1] = v;
    __syncthreads();

    if (t == 0) {
        float v_diff = fminf(ksel[0][0], ksel[1][0]);
        float v_same = fmaxf(ksel[0][1], ksel[1][1]);
        float val = (tgt[i] == tgt[j]) ? v_same : v_diff;
        Dmat[i * B + j] = val;
        Dmat[j * B + i] = val;
    }
}

// ---------------------------------------------------------------------------
// K4: hardest positive / hardest negative per row + mean margin-ranking loss.
// ---------------------------------------------------------------------------
__global__ __launch_bounds__(128) void final_kernel(const float* __restrict__ Dmat,
                                                    const int* __restrict__ tgt,
                                                    float* __restrict__ out) {
    int i = threadIdx.x;
    int ti = tgt[i];
    float ap = -INFINITY, an = INFINITY;
    for (int jj = 0; jj < B; ++jj) {
        float v = (jj == i) ? 0.f : Dmat[i * B + jj];
        if (tgt[jj] == ti) ap = fmaxf(ap, v);
        else an = fminf(an, v);
    }
    float term = ap - an + MARGINF;
    term = term > 0.f ? term : 0.f;

    __shared__ float red[128];
    red[i] = term;
    __syncthreads();
    for (int off = 64; off >= 1; off >>= 1) {
        if (i < off) red[i] += red[i + off];
        __syncthreads();
    }
    if (i == 0) out[0] = red[0] / (float)B;
}

// ---------------------------------------------------------------------------
extern "C" void kernel_launch(void* const* d_in, const int* in_sizes, int n_in,
                              void* d_out, int out_size, void* d_ws, size_t ws_size,
                              hipStream_t stream) {
    const float* X = (const float*)d_in[0];   // (128, 32, 128) f32
    const int* tgt = (const int*)d_in[1];     // (128,) int
    float* out = (float*)d_out;

    // workspace: Zn bf16 2MB | sqv 16KB | rowsum 2MB | rowmin 2MB | Dmat 64KB
    unsigned short* Zn = (unsigned short*)d_ws;
    float* sqv = (float*)(Zn + (size_t)NV * 256);
    float* rowsum = sqv + NV;
    float* rowmin = rowsum + (size_t)B * B * S;
    float* Dmat = rowmin + (size_t)B * B * S;

    norm_kernel<<<NV, 64, 0, stream>>>(X, Zn, sqv);

    int nblk2 = 2112;  // sum over jg of (4*jg+4)
    pair_block_kernel<<<nblk2, 256, 5 * 8192 * sizeof(unsigned short), stream>>>(Zn, sqv, rowsum, rowmin);

    int npair = B * (B - 1) / 2;  // 8128
    pair_select_kernel<<<npair, 64, 0, stream>>>(rowsum, rowmin, tgt, Dmat);

    final_kernel<<<1, 128, 0, stream>>>(Dmat, tgt, out);
}

// Round 8
// 47.547 us; speedup vs baseline: 7.3923x; 1.3595x over previous
//
#include <hip/hip_runtime.h>
#include <math.h>

#define B 128
#define S 32
#define Dm 128
#define NV (B * S)
#define MARGINF 0.3f

typedef __attribute__((ext_vector_type(8))) short short8;
typedef __attribute__((ext_vector_type(16))) float f32x16;

#define GLOBAL_AS __attribute__((address_space(1)))
#define LDS_AS __attribute__((address_space(3)))

// RNE f32 -> bf16 (finite inputs only)
__device__ inline unsigned short f2bf(float f) {
    unsigned u = __float_as_uint(f);
    unsigned r = u + 0x7FFF + ((u >> 16) & 1);
    return (unsigned short)(r >> 16);
}
__device__ inline float bf2f(unsigned short h) {
    return __uint_as_float(((unsigned)h) << 16);
}

// ---------------------------------------------------------------------------
// K1: L2-normalize each vector, quantize to bf16 (hi only), store z (128 bf16)
// and sqv = |z|^2 computed FROM THE QUANTIZED z (self-consistent geometry:
// d2 = sq_p + sq_q - 2<z_p,z_q> = |z_p - z_q|^2 >= 0 up to f32 rounding).
// ---------------------------------------------------------------------------
__global__ __launch_bounds__(64) void norm_kernel(const float* __restrict__ X,
                                                  unsigned short* __restrict__ Zn,
                                                  float* __restrict__ sqv) {
    int v = blockIdx.x;
    int l = threadIdx.x;
    const float* xr = X + (size_t)v * Dm;
    float a = xr[l];
    float b = xr[l + 64];
    float ss = a * a + b * b;
    for (int off = 32; off >= 1; off >>= 1) ss += __shfl_down(ss, off);
    ss = __shfl(ss, 0);
    float inv = 1.0f / fmaxf(sqrtf(ss), 1e-12f);
    unsigned short ha = f2bf(a * inv), hb = f2bf(b * inv);
    float fa = bf2f(ha), fb = bf2f(hb);
    float s2 = fa * fa + fb * fb;
    for (int off = 32; off >= 1; off >>= 1) s2 += __shfl_down(s2, off);

    unsigned short* zr = Zn + (size_t)v * Dm;
    zr[l] = ha;
    zr[64 + l] = hb;
    if (l == 0) sqv[v] = __shfl(s2, 0);
}

// ---------------------------------------------------------------------------
// K1b: per-tracklet diagonal row sums: diagsum[i][p] = sum_q exp(|z_p - z_q|)
// over the 32 vectors of tracklet i (E_ii is symmetric: rowsum == colsum).
// One wave per tracklet; panel staged via global_load_lds with the same
// source-side XOR swizzle used everywhere (slot ^= row&7 on 16B slots).
// ---------------------------------------------------------------------------
__global__ __launch_bounds__(64) void diag_kernel(const unsigned short* __restrict__ Zn,
                                                  const float* __restrict__ sqv,
                                                  float* __restrict__ diagsum) {
    int i = blockIdx.x;
    __shared__ unsigned short lds[4096];   // 32 rows x 128 bf16 = 8 KB
    int lane = threadIdx.x;
    int slot = lane & 15;
    int rhi = lane >> 4;

#pragma unroll
    for (int k = 0; k < 8; ++k) {
        int row = (k << 2) | rhi;
        const unsigned short* gsrc =
            Zn + ((size_t)i << 12) + (row << 7) + ((slot ^ (row & 7)) << 3);
        unsigned short* ldst = lds + k * 512;
        __builtin_amdgcn_global_load_lds((const GLOBAL_AS void*)(const void*)gsrc,
                                         (LDS_AS void*)(void*)ldst, 16, 0, 0);
    }
    __syncthreads();

    int lq = lane & 31;
    int kh = lane >> 5;
    int sx = lq & 7;

    f32x16 acc;
#pragma unroll
    for (int r = 0; r < 16; ++r) acc[r] = 0.f;
#pragma unroll
    for (int ks = 0; ks < 8; ++ks) {
        int off = (lq << 7) + (((2 * ks + kh) ^ sx) << 3);
        short8 av = *(const short8*)(lds + off);
        acc = __builtin_amdgcn_mfma_f32_32x32x16_bf16(av, av, acc, 0, 0, 0);
    }

    float sql = sqv[(i << 5) + lq];
    float s = 0.f;
#pragma unroll
    for (int r = 0; r < 16; ++r) {
        int m = (r & 3) + 8 * (r >> 2) + 4 * kh;
        float sqm = __shfl(sql, m);
        float d2 = sqm + sql - 2.f * acc[r];
        s += expf(sqrtf(fmaxf(d2, 1e-12f)));
    }
    s += __shfl_xor(s, 32);
    if (lane < 32) diagsum[(i << 5) + lq] = s;
}

// ---------------------------------------------------------------------------
// K2: triangular block (jg, i), i in [0, 4jg+3). Stages panel i + 4 j-panels
// (8 KB each, 40 KB total) via global_load_lds (linear LDS dest, XOR swizzle
// on the per-lane GLOBAL source, same involution on the ds_read side).
// Wave w handles pair (i, j=4jg+w) when j > i:
//   acc  = G   = Zi . Zj^T  (E[m][n],  n = lane)   -> col stats in-lane
//   acc2 = G^T = Zj . Zi^T  (E[n][m],  n = lane)   -> row stats in-lane
// Then fused selection: a[p] = rmin/(diag_i[p]+rsum), c[q] = cmin/(diag_j[q]
// +csum); bitonic sort (ascending) of a|c across the two 32-lane halves;
// 3rd/6th largest via lanes 29/26; write Dmat[i][j] = Dmat[j][i].
// ---------------------------------------------------------------------------
__global__ __launch_bounds__(256) void pair_kernel(const unsigned short* __restrict__ Zn,
                                                   const float* __restrict__ sqv,
                                                   const float* __restrict__ diagsum,
                                                   const int* __restrict__ tgt,
                                                   float* __restrict__ Dmat) {
    // unrank t0 -> (jg, i): start(jg) = 2*jg^2 + jg, i in [0, 4jg+3)
    int t0 = blockIdx.x;
    int jg = (int)((sqrtf(8.f * (float)t0 + 1.f) - 1.f) * 0.25f);
    while (jg > 0 && t0 < 2 * jg * jg + jg) --jg;
    while (t0 >= 2 * (jg + 1) * (jg + 1) + (jg + 1)) ++jg;
    int i = t0 - (2 * jg * jg + jg);
    int jbase = jg * 4;

    extern __shared__ unsigned short lds[];   // 5 * 4096 ushort = 40 KB

    int t = threadIdx.x;
    int w = t >> 6;
    int lane = t & 63;

    // ---- staging: 40 segments of 1 KB; wave w owns segs [w*10, w*10+10) ----
    {
        int slot = lane & 15;
        int rhi = lane >> 4;
#pragma unroll
        for (int k = 0; k < 10; ++k) {
            int seg = w * 10 + k;                  // uniform per wave
            int panel = seg >> 3;
            int row = ((seg & 7) << 2) | rhi;
            int vec = (panel == 0) ? i : (jbase + panel - 1);
            const unsigned short* gsrc =
                Zn + ((size_t)vec << 12) + (row << 7) + ((slot ^ (row & 7)) << 3);
            unsigned short* ldst = lds + seg * 512;
            __builtin_amdgcn_global_load_lds((const GLOBAL_AS void*)(const void*)gsrc,
                                             (LDS_AS void*)(void*)ldst, 16, 0, 0);
        }
    }
    __syncthreads();

    int j = jbase + w;
    if (j <= i) return;       // no further barriers

    const unsigned short* Pi = lds;
    const unsigned short* Pj = lds + (w + 1) * 4096;
    int lq = lane & 31;
    int kh = lane >> 5;
    int sx = lq & 7;

    f32x16 acc, acc2;
#pragma unroll
    for (int r = 0; r < 16; ++r) { acc[r] = 0.f; acc2[r] = 0.f; }

#pragma unroll
    for (int ks = 0; ks < 8; ++ks) {
        int off = (lq << 7) + (((2 * ks + kh) ^ sx) << 3);
        short8 av = *(const short8*)(Pi + off);
        short8 bv = *(const short8*)(Pj + off);
        acc  = __builtin_amdgcn_mfma_f32_32x32x16_bf16(av, bv, acc, 0, 0, 0);
        acc2 = __builtin_amdgcn_mfma_f32_32x32x16_bf16(bv, av, acc2, 0, 0, 0);
    }

    // ---- epilogue: both stat directions via in-lane reg reductions ----
    float sqi_l = sqv[(i << 5) + lq];
    float sqj_l = sqv[(j << 5) + lq];
    float di = diagsum[(i << 5) + lq];
    float dj = diagsum[(j << 5) + lq];

    float csum = 0.f, cmin = INFINITY, rsum = 0.f, rmin = INFINITY;
#pragma unroll
    for (int r = 0; r < 16; ++r) {
        int m = (r & 3) + 8 * (r >> 2) + 4 * kh;
        float sqim = __shfl(sqi_l, m);
        float sqjm = __shfl(sqj_l, m);
        float d2a = sqim + sqj_l - 2.f * acc[r];    // E[m][lq]: col q=lq
        float ea = expf(sqrtf(fmaxf(d2a, 1e-12f)));
        csum += ea; cmin = fminf(cmin, ea);
        float d2b = sqi_l + sqjm - 2.f * acc2[r];   // E[lq][m]: row p=lq
        float eb = expf(sqrtf(fmaxf(d2b, 1e-12f)));
        rsum += eb; rmin = fminf(rmin, eb);
    }
    csum += __shfl_xor(csum, 32);
    cmin = fminf(cmin, __shfl_xor(cmin, 32));
    rsum += __shfl_xor(rsum, 32);
    rmin = fminf(rmin, __shfl_xor(rmin, 32));

    float aval = rmin / (di + rsum);
    float cval = cmin / (dj + csum);

    // bitonic ascending sort within each 32-lane half: half0 = a, half1 = c
    float v = (lane < 32) ? aval : cval;
#pragma unroll
    for (int k = 2; k <= 32; k <<= 1) {
#pragma unroll
        for (int mm = k >> 1; mm >= 1; mm >>= 1) {
            float o = __shfl_xor(v, mm);
            bool asc = ((lq & k) == 0);
            bool upper = (lq & mm) != 0;
            float mn = fminf(v, o), mx = fmaxf(v, o);
            v = (asc == upper) ? mx : mn;
        }
    }
    // ascending: 3rd largest at lane 29, 6th at lane 26 (per half)
    float ta3 = __shfl(v, 29), ta6 = __shfl(v, 26);
    float tc3 = __shfl(v, 61), tc6 = __shfl(v, 58);

    if (lane == 0) {
        float v_same = fmaxf(ta6, tc6);
        float v_diff = fminf(ta3, tc3);
        float val = (tgt[i] == tgt[j]) ? v_same : v_diff;
        Dmat[i * B + j] = val;
        Dmat[j * B + i] = val;
    }
}

// ---------------------------------------------------------------------------
// K4: hardest positive / hardest negative per row + mean margin-ranking loss.
// ---------------------------------------------------------------------------
__global__ __launch_bounds__(128) void final_kernel(const float* __restrict__ Dmat,
                                                    const int* __restrict__ tgt,
                                                    float* __restrict__ out) {
    int i = threadIdx.x;
    int ti = tgt[i];
    float ap = -INFINITY, an = INFINITY;
    for (int jj = 0; jj < B; ++jj) {
        float v = (jj == i) ? 0.f : Dmat[i * B + jj];
        if (tgt[jj] == ti) ap = fmaxf(ap, v);
        else an = fminf(an, v);
    }
    float term = ap - an + MARGINF;
    term = term > 0.f ? term : 0.f;

    __shared__ float red[128];
    red[i] = term;
    __syncthreads();
    for (int off = 64; off >= 1; off >>= 1) {
        if (i < off) red[i] += red[i + off];
        __syncthreads();
    }
    if (i == 0) out[0] = red[0] / (float)B;
}

// ---------------------------------------------------------------------------
extern "C" void kernel_launch(void* const* d_in, const int* in_sizes, int n_in,
                              void* d_out, int out_size, void* d_ws, size_t ws_size,
                              hipStream_t stream) {
    const float* X = (const float*)d_in[0];   // (128, 32, 128) f32
    const int* tgt = (const int*)d_in[1];     // (128,) int
    float* out = (float*)d_out;

    // ws: Zn bf16 1MB | sqv 16KB | diagsum 16KB | Dmat 64KB
    unsigned short* Zn = (unsigned short*)d_ws;
    float* sqv = (float*)(Zn + (size_t)NV * Dm);
    float* diagsum = sqv + NV;
    float* Dmat = diagsum + B * S;

    norm_kernel<<<NV, 64, 0, stream>>>(X, Zn, sqv);
    diag_kernel<<<B, 64, 0, stream>>>(Zn, sqv, diagsum);

    int nblk = 2080;  // sum over jg=0..31 of (4*jg+3)
    pair_kernel<<<nblk, 256, 5 * 4096 * sizeof(unsigned short), stream>>>(Zn, sqv, diagsum, tgt, Dmat);

    final_kernel<<<1, 128, 0, stream>>>(Dmat, tgt, out);
}